// Round 11
// baseline (404.943 us; speedup 1.0000x reference)
//
#include <hip/hip_runtime.h>
#include <hip/hip_bf16.h>
#include <cstdint>

// GQA forward: B=2, N=2048, D_IN=2048, H=32, KV=8, G=4, DH=64
// Round 11: attn V de-staged (m169 precedent): vb fragments read directly from
// Vtg (L2-resident 256KB/(b,kv); wave-identical addresses -> L1 hits), K stays
// LDS-staged. Cuts attn LDS reads 147->83 KB/block-iter (-44%) and halves the
// stage DMA. LDS 48KB. GEMMs = R9 full-fill BK=64. prep/transpose = R8.

#define B_    2
#define N_    2048
#define DIN_  2048
#define H_    32
#define KV_   8
#define DH_   64
#define M_    4096      // B*N
#define NQKV_ 3072      // H*DH + 2*KV*DH

typedef float f32x4 __attribute__((ext_vector_type(4)));
typedef __bf16 bf16x8 __attribute__((ext_vector_type(8)));
typedef unsigned short u16x8 __attribute__((ext_vector_type(8)));

__device__ __forceinline__ unsigned short f32_to_bf16_bits(float f) {
  unsigned int u = __float_as_uint(f);
  u = (u + 0x7FFFu + ((u >> 16) & 1u)) >> 16;   // RNE
  return (unsigned short)u;
}

__device__ __forceinline__ void gload_lds16(const void* g, void* l) {
  __builtin_amdgcn_global_load_lds(
      (__attribute__((address_space(1))) void*)(g),
      (__attribute__((address_space(3))) void*)(l), 16, 0, 0);
}

// ---------------- fused prep: cast x -> bf16 (task 0), transpose-cast W (tasks 1-4) ----------------
__global__ __launch_bounds__(256) void prep(
    const float* __restrict__ x, const float* __restrict__ Wq,
    const float* __restrict__ Wk, const float* __restrict__ Wv,
    const float* __restrict__ Wo,
    unsigned short* __restrict__ Xb, unsigned short* __restrict__ Wqkv,
    unsigned short* __restrict__ Wot, float qscale) {
  const int task = blockIdx.y, tid = threadIdx.x;
  if (task == 0) {
    size_t base = (size_t)blockIdx.x * 1024;   // float4 index, 1024/block
#pragma unroll
    for (int t = 0; t < 4; ++t) {
      size_t i = base + t * 256 + tid;         // lane-consecutive
      float4 v = ((const float4*)x)[i];
      ushort4 o;
      o.x = f32_to_bf16_bits(v.x);
      o.y = f32_to_bf16_bits(v.y);
      o.z = f32_to_bf16_bits(v.z);
      o.w = f32_to_bf16_bits(v.w);
      ((ushort4*)Xb)[i] = o;
    }
    return;
  }
  const float* src;
  unsigned short* dst;
  int NC, off;
  float scale = 1.0f;
  switch (task) {
    case 1: src = Wq; dst = Wqkv; NC = 2048; off = 0;    scale = qscale; break;
    case 2: src = Wk; dst = Wqkv; NC = 512;  off = 2048; break;
    case 3: src = Wv; dst = Wqkv; NC = 512;  off = 2560; break;
    default: src = Wo; dst = Wot; NC = 2048; off = 0;    break;
  }
  const int nbn = NC >> 6;                     // 64-col n-blocks
  if (blockIdx.x >= 32 * nbn) return;          // 32 k-blocks of 64
  const int n0 = (blockIdx.x % nbn) * 64, k0 = (blockIdx.x / nbn) * 64;

  __shared__ float tile[64][68];               // row stride 272B (16B-aligned)
  const int tx = tid & 15, ty = tid >> 4;      // 16x16 load threads
#pragma unroll
  for (int i = 0; i < 4; ++i) {
    float4 v = *(const float4*)&src[(size_t)(k0 + i * 16 + ty) * NC + n0 + tx * 4];
    *(float4*)&tile[i * 16 + ty][tx * 4] = v;
  }
  __syncthreads();
  const int n = tid >> 2, kc = (tid & 3) * 16; // 4 threads/row, 16 k each
  unsigned short* drow = dst + (size_t)(off + n0 + n) * 2048 + k0 + kc;
#pragma unroll
  for (int h = 0; h < 2; ++h) {
    u16x8 o;
#pragma unroll
    for (int j = 0; j < 8; ++j)
      o[j] = f32_to_bf16_bits(tile[kc + h * 8 + j][n] * scale);
    *(u16x8*)(drow + h * 8) = o;
  }
}

// ---------- pre-transpose V: QKV[:,2560+kv*64+d] -> Vtg[(bkv*64+d)*2048 + n] ----------
__global__ __launch_bounds__(256) void transpose_v(
    const unsigned short* __restrict__ QKV, unsigned short* __restrict__ Vtg) {
  __shared__ unsigned short t[64][72];
  int nt = blockIdx.x, bkv = blockIdx.y;
  int b = bkv >> 3, kv = bkv & 7;
  int tid = threadIdx.x;
  int row = tid >> 2, c = (tid & 3) * 16;
  const unsigned short* src =
      QKV + (size_t)(b * N_ + nt * 64 + row) * NQKV_ + 2560 + kv * 64;
  *(u16x8*)&t[row][c]     = *(const u16x8*)(src + c);
  *(u16x8*)&t[row][c + 8] = *(const u16x8*)(src + c + 8);
  __syncthreads();
  int d = tid >> 2;
  unsigned short* dst = Vtg + ((size_t)bkv * 64 + d) * N_ + nt * 64 + c;
  u16x8 o0, o1;
#pragma unroll
  for (int i = 0; i < 8; ++i) { o0[i] = t[c + i][d]; o1[i] = t[c + 8 + i][d]; }
  *(u16x8*)dst = o0;
  *(u16x8*)(dst + 8) = o1;
}

// ------------- bf16 GEMM, BM x BN tile, 8-wave (2x4), BK=64 (R7 schedule) -------------
template <int BM, int BN, bool OUT_BF16, bool BIAS>
__global__ __launch_bounds__(512, 2) void gemm256p(
    const unsigned short* __restrict__ A,
    const unsigned short* __restrict__ Bt,
    void* __restrict__ Cv,
    const float* __restrict__ bias,
    int Nn, int K, int nbx) {
  constexpr int AL = BM / 64;                  // A gloads/thread/stage
  constexpr int BL = BN / 64;                  // B gloads/thread/stage
  constexpr int STL = AL + BL;
  constexpr int RM = BM / 2;                   // rows per wave
  constexpr int CW = BN / 4;                   // cols per wave
  constexpr int MI = RM / 16;
  constexpr int NI = CW / 16;
  constexpr int NP = MI / 2;                   // MFMA clusters (A pairs)

  __shared__ unsigned short ldsA[2][BM * 64];
  __shared__ unsigned short ldsB[2][BN * 64];

  const int tid = threadIdx.x;
  const int lane = tid & 63;
  const int wave = tid >> 6;                   // 0..7
  const int wm = wave >> 2, wn = wave & 3;     // 2x4 wave grid
  const int l16 = lane & 15, quad = lane >> 4;

  // T1: XCD-aware bijective swizzle (grid = 256, multiple of 8)
  const int nwg = gridDim.x;
  const int orig = blockIdx.x;
  const int bid = (orig & 7) * (nwg >> 3) + (orig >> 3);
  const int m0 = (bid / nbx) * BM, n0 = (bid % nbx) * BN;

  const int T = K >> 6;                        // K-tiles of 64

  auto stage = [&](int c) {
    const int buf = c & 1;
#pragma unroll
    for (int i = 0; i < AL; ++i) {
      int off = i * 8192 + tid * 16;
      int row = off >> 7;
      int kch = ((off >> 4) & 7) ^ (row & 7);
      gload_lds16(A + (size_t)(m0 + row) * K + c * 64 + kch * 8,
                  (char*)&ldsA[buf][0] + off);
    }
#pragma unroll
    for (int i = 0; i < BL; ++i) {
      int off = i * 8192 + tid * 16;
      int row = off >> 7;
      int kch = ((off >> 4) & 7) ^ (row & 7);
      gload_lds16(Bt + (size_t)(n0 + row) * K + c * 64 + kch * 8,
                  (char*)&ldsB[buf][0] + off);
    }
  };

  const int sw7 = l16 & 7;
  const int cA0 = ((0 * 4 + quad) ^ sw7) * 16;
  const int cA1 = ((1 * 4 + quad) ^ sw7) * 16;
  const int rowA = (wm * RM + l16) * 128;      // byte row base, + mi*2048
  const int rowB = (wn * CW + l16) * 128;      // + ni*2048

  f32x4 acc[MI][NI] = {};

  stage(0);
  stage(1);

  for (int c = 0; c < T; ++c) {
    if (c + 1 < T) {
      if constexpr (STL == 6)      asm volatile("s_waitcnt vmcnt(6)" ::: "memory");
      else if constexpr (STL == 7) asm volatile("s_waitcnt vmcnt(7)" ::: "memory");
      else                         asm volatile("s_waitcnt vmcnt(8)" ::: "memory");
    } else {
      asm volatile("s_waitcnt vmcnt(0)" ::: "memory");
    }
    __builtin_amdgcn_s_barrier();
    asm volatile("" ::: "memory");             // pin LDS reads below barrier

    const char* Ar = (const char*)&ldsA[c & 1][0];
    const char* Br = (const char*)&ldsB[c & 1][0];

    // batch 1: all B fragments (reg-resident for whole K-tile) + A pair 0
    bf16x8 b[NI][2];
#pragma unroll
    for (int ni = 0; ni < NI; ++ni) {
      b[ni][0] = *(const bf16x8*)(Br + rowB + ni * 2048 + cA0);
      b[ni][1] = *(const bf16x8*)(Br + rowB + ni * 2048 + cA1);
    }
    bf16x8 ap[2][2][2];                        // [pair parity][mi_loc][ks]
#pragma unroll
    for (int ml = 0; ml < 2; ++ml) {
      ap[0][ml][0] = *(const bf16x8*)(Ar + rowA + ml * 2048 + cA0);
      ap[0][ml][1] = *(const bf16x8*)(Ar + rowA + ml * 2048 + cA1);
    }
    asm volatile("s_waitcnt lgkmcnt(0)" ::: "memory");
    __builtin_amdgcn_sched_barrier(0);

#pragma unroll
    for (int p = 0; p < NP; ++p) {
      if (p < NP - 1) {                        // prefetch next A pair
        const int nx = (p + 1) & 1;
#pragma unroll
        for (int ml = 0; ml < 2; ++ml) {
          int mi = (p + 1) * 2 + ml;
          ap[nx][ml][0] = *(const bf16x8*)(Ar + rowA + mi * 2048 + cA0);
          ap[nx][ml][1] = *(const bf16x8*)(Ar + rowA + mi * 2048 + cA1);
        }
      }
      __builtin_amdgcn_sched_barrier(0);
      __builtin_amdgcn_s_setprio(1);
#pragma unroll
      for (int ml = 0; ml < 2; ++ml)
#pragma unroll
        for (int ni = 0; ni < NI; ++ni)
#pragma unroll
          for (int ks = 0; ks < 2; ++ks)
            acc[p * 2 + ml][ni] = __builtin_amdgcn_mfma_f32_16x16x32_bf16(
                ap[p & 1][ml][ks], b[ni][ks], acc[p * 2 + ml][ni], 0, 0, 0);
      __builtin_amdgcn_s_setprio(0);
      if (p < NP - 1) {
        asm volatile("s_waitcnt lgkmcnt(0)" ::: "memory");
        __builtin_amdgcn_sched_barrier(0);
      }
    }

    asm volatile("" ::: "memory");
    __builtin_amdgcn_s_barrier();              // all waves' reads retired
    asm volatile("" ::: "memory");
    if (c + 2 < T) stage(c + 2);               // overwrite this buf for c+2
  }

  // epilogue
  unsigned short* Cb = (unsigned short*)Cv;
  float* Cf = (float*)Cv;
#pragma unroll
  for (int mi = 0; mi < MI; ++mi) {
    int rrow = m0 + wm * RM + mi * 16 + quad * 4;
#pragma unroll
    for (int ni = 0; ni < NI; ++ni) {
      int col = n0 + wn * CW + ni * 16 + l16;
      float bv = BIAS ? bias[col] : 0.0f;
#pragma unroll
      for (int r = 0; r < 4; ++r) {
        float v = acc[mi][ni][r] + bv;
        if (OUT_BF16)
          Cb[(size_t)(rrow + r) * Nn + col] = f32_to_bf16_bits(v);
        else
          Cf[(size_t)(rrow + r) * Nn + col] = v;
      }
    }
  }
}

// ---------------- flash attention (causal) ----------------
// R11: 8 waves x 1 strip (R10 partition) but V is NOT LDS-staged: vb fragments
// come straight from Vtg global (identical addresses across the 8 waves -> L1
// hit after first wave; 16-lane groups read 64B-contiguous segments). K stays
// LDS-staged (dbuf). LDS 48KB: Ks 16KB + Ps 32KB.
__global__ __launch_bounds__(512, 4) void attn_fwd(
    const unsigned short* __restrict__ QKV,   // (4096, 3072) bf16 [Q|K|V]
    const unsigned short* __restrict__ Vtg,   // (16*64, 2048) bf16 V^T per (b,kv)
    unsigned short* __restrict__ Ctx) {       // (4096, 2048) bf16
  __shared__ unsigned short Ks[2][64 * 64];     // 16 KB
  __shared__ unsigned short Ps[2][8][16 * 64];  // 32 KB [parity][wave]

  const int p = blockIdx.x;                      // 0..15
  const int kv = blockIdx.y >> 1, hp = blockIdx.y & 1;
  const int b = blockIdx.z;
  const int tid = threadIdx.x, lane = tid & 63, wave = tid >> 6;  // 0..7
  const int l16 = lane & 15, quad = lane >> 4;
  const int h = kv * 4 + hp * 2 + (wave >> 2);
  const int rstrip = (wave & 3) * 16;
  const size_t baserow = (size_t)b * N_;
  const unsigned short* Kg = QKV + 2048 + kv * 64;
  const unsigned short* Vg = Vtg + (size_t)(b * KV_ + kv) * 64 * N_;
  const unsigned short* Qbase = QKV + baserow * NQKV_ + h * 64;
  const int sw = l16 & 7;

  auto stageK = [&](int j, int buf) {
    int c = tid;                               // 512 chunks of 16B = 8KB tile
    int row = c >> 3, off = ((c & 7) ^ (row & 7)) * 8;
    gload_lds16(Kg + (baserow + j * 64 + row) * NQKV_ + off,
                (char*)Ks[buf] + c * 16);
  };

#pragma unroll 1
  for (int phase = 0; phase < 2; ++phase) {
    const int qtile = phase ? p : 31 - p;
    const int q0 = qtile * 64;

    // Q fragments direct from global (A-layout: row=l16, k=quad*8+j)
    bf16x8 qa[2];
#pragma unroll
    for (int ks = 0; ks < 2; ++ks)
      qa[ks] = *(const bf16x8*)(Qbase +
          (size_t)(q0 + rstrip + l16) * NQKV_ + ks * 32 + quad * 8);

    f32x4 oacc[4] = {};
    float lp[4] = {};

    __syncthreads();            // previous phase's K readers done
    stageK(0, 0);

    for (int j = 0; j <= qtile; ++j) {
      __syncthreads();          // staged buf visible (drains vmcnt)
      const int buf = j & 1;
      if (j < qtile) stageK(j + 1, buf ^ 1);

      // V fragments direct from global — issue EARLY so QK+softmax hides the
      // L1/L2 latency. Address = exactly what the old LDS Vs held (XOR cancels).
      bf16x8 vb[2][4];
#pragma unroll
      for (int ks = 0; ks < 2; ++ks)
#pragma unroll
        for (int di = 0; di < 4; ++di)
          vb[ks][di] = *(const bf16x8*)(Vg +
              (size_t)(di * 16 + l16) * N_ + j * 64 + (ks * 4 + quad) * 8);

      // K fragments from LDS
      bf16x8 kb[2][4];
#pragma unroll
      for (int ks = 0; ks < 2; ++ks)
#pragma unroll
        for (int ni = 0; ni < 4; ++ni)
          kb[ks][ni] = *(const bf16x8*)&Ks[buf][(ni * 16 + l16) * 64 +
                                               ((ks * 4 + quad) ^ sw) * 8];

      // S = Q K^T -> mask -> exp2 -> pack to Ps[parity][wave]
      f32x4 sc[4] = {};
      __builtin_amdgcn_s_setprio(1);
#pragma unroll
      for (int ks = 0; ks < 2; ++ks)
#pragma unroll
        for (int ni = 0; ni < 4; ++ni)
          sc[ni] = __builtin_amdgcn_mfma_f32_16x16x32_bf16(
              qa[ks], kb[ks][ni], sc[ni], 0, 0, 0);
      __builtin_amdgcn_s_setprio(0);
      if (j == qtile) {   // causal mask, diagonal tile only
        const int qrow = q0 + rstrip + quad * 4;
#pragma unroll
        for (int ni = 0; ni < 4; ++ni) {
          int kcol = q0 + ni * 16 + l16;
#pragma unroll
          for (int r = 0; r < 4; ++r)
            if (kcol > qrow + r) sc[ni][r] = -1e30f;
        }
      }
      unsigned short* Pw = &Ps[buf][wave][0];
#pragma unroll
      for (int ni = 0; ni < 4; ++ni) {
        const int cl = ni * 2 + (l16 >> 3);
#pragma unroll
        for (int r = 0; r < 4; ++r) {
          float pe = __builtin_amdgcn_exp2f(sc[ni][r]);
          lp[r] += pe;
          int row = quad * 4 + r;
          Pw[row * 64 + ((cl ^ (row & 7)) * 8) + (l16 & 7)] =
              (unsigned short)(__float_as_uint(pe) >> 16);
        }
      }

      // P read back in A-layout; PV MFMA (vb waits handled by compiler vmcnt)
      bf16x8 pa[2];
#pragma unroll
      for (int ks = 0; ks < 2; ++ks)
        pa[ks] = *(const bf16x8*)&Ps[buf][wave][l16 * 64 +
                                               ((ks * 4 + quad) ^ sw) * 8];
      __builtin_amdgcn_s_setprio(1);
#pragma unroll
      for (int ks = 0; ks < 2; ++ks)
#pragma unroll
        for (int di = 0; di < 4; ++di)
          oacc[di] = __builtin_amdgcn_mfma_f32_16x16x32_bf16(
              pa[ks], vb[ks][di], oacc[di], 0, 0, 0);
      __builtin_amdgcn_s_setprio(0);
    }

    // normalize + write
    float inv[4];
#pragma unroll
    for (int r = 0; r < 4; ++r) {
      float v = lp[r];
#pragma unroll
      for (int off = 1; off < 16; off <<= 1) v += __shfl_xor(v, off);
      inv[r] = 1.0f / v;
    }
#pragma unroll
    for (int di = 0; di < 4; ++di)
#pragma unroll
      for (int r = 0; r < 4; ++r) {
        size_t row = baserow + q0 + rstrip + quad * 4 + r;
        Ctx[row * 2048 + h * 64 + di * 16 + l16] =
            f32_to_bf16_bits(oacc[di][r] * inv[r]);
      }
  }
}

extern "C" void kernel_launch(void* const* d_in, const int* in_sizes, int n_in,
                              void* d_out, int out_size, void* d_ws, size_t ws_size,
                              hipStream_t stream) {
  const float* x  = (const float*)d_in[0];
  const float* Wq = (const float*)d_in[1];
  const float* Wk = (const float*)d_in[2];
  const float* Wv = (const float*)d_in[3];
  const float* Wo = (const float*)d_in[4];
  const float* bo = (const float*)d_in[5];
  float* out = (float*)d_out;

  // workspace layout (bf16 = ushort): 60 MB total
  unsigned short* Xb   = (unsigned short*)d_ws;              // 4096x2048 (16 MB)
  unsigned short* Wqkv = Xb + (size_t)M_ * DIN_;             // 3072x2048 (12 MB)
  unsigned short* QKV  = Wqkv + (size_t)NQKV_ * DIN_;        // 4096x3072 (24 MB)
  unsigned short* Wot  = QKV + (size_t)M_ * NQKV_;           // 2048x2048 (8 MB)
  unsigned short* Ctx  = Xb;    // alias: Xb dead after QKV GEMM
  unsigned short* Vtg  = Wqkv;  // alias: Wqkv dead after QKV GEMM (4 MB)

  const float kQScale = 0.125f * 1.44269504088896340736f;  // (1/sqrt(DH)) * log2(e)

  prep<<<dim3(2048, 5), 256, 0, stream>>>(x, Wq, Wk, Wv, Wo, Xb, Wqkv, Wot, kQScale);

  // QKV GEMM: (4096x2048) @ (3072x2048)^T, 256x192 tiles -> 16x16 = 256 blocks
  gemm256p<256, 192, true, false><<<dim3(256), 512, 0, stream>>>(
      Xb, Wqkv, QKV, nullptr, NQKV_, DIN_, NQKV_ / 192);

  transpose_v<<<dim3(N_ / 64, B_ * KV_), 256, 0, stream>>>(QKV, Vtg);

  attn_fwd<<<dim3(16, 16, 2), 512, 0, stream>>>(QKV, Vtg, Ctx);

  // out GEMM: (4096x2048) @ (2048x2048)^T, 128x256 tiles -> 32x8 = 256 blocks
  gemm256p<128, 256, false, true><<<dim3(256), 512, 0, stream>>>(
      Ctx, Wot, out, bo, DIN_, 2048, DIN_ / 256);
}

// Round 12
// 277.915 us; speedup vs baseline: 1.4571x; 1.4571x over previous
//
#include <hip/hip_runtime.h>
#include <hip/hip_bf16.h>
#include <cstdint>

// GQA forward: B=2, N=2048, D_IN=2048, H=32, KV=8, G=4, DH=64
// Round 12: REVERT attn to R10 (verified 67.6us; R11's V-de-stage was 2.9x
// worse -- strided 4KB/lane global V reads; V staging via LDS is structurally
// required). out GEMM tile 128x256 -> 256x128 (same 256-block full fill,
// MFMA-denser body). GEMMs otherwise R9; prep/transpose R8.

#define B_    2
#define N_    2048
#define DIN_  2048
#define H_    32
#define KV_   8
#define DH_   64
#define M_    4096      // B*N
#define NQKV_ 3072      // H*DH + 2*KV*DH

typedef float f32x4 __attribute__((ext_vector_type(4)));
typedef __bf16 bf16x8 __attribute__((ext_vector_type(8)));
typedef unsigned short u16x8 __attribute__((ext_vector_type(8)));

__device__ __forceinline__ unsigned short f32_to_bf16_bits(float f) {
  unsigned int u = __float_as_uint(f);
  u = (u + 0x7FFFu + ((u >> 16) & 1u)) >> 16;   // RNE
  return (unsigned short)u;
}

__device__ __forceinline__ void gload_lds16(const void* g, void* l) {
  __builtin_amdgcn_global_load_lds(
      (__attribute__((address_space(1))) void*)(g),
      (__attribute__((address_space(3))) void*)(l), 16, 0, 0);
}

// ---------------- fused prep: cast x -> bf16 (task 0), transpose-cast W (tasks 1-4) ----------------
__global__ __launch_bounds__(256) void prep(
    const float* __restrict__ x, const float* __restrict__ Wq,
    const float* __restrict__ Wk, const float* __restrict__ Wv,
    const float* __restrict__ Wo,
    unsigned short* __restrict__ Xb, unsigned short* __restrict__ Wqkv,
    unsigned short* __restrict__ Wot, float qscale) {
  const int task = blockIdx.y, tid = threadIdx.x;
  if (task == 0) {
    size_t base = (size_t)blockIdx.x * 1024;   // float4 index, 1024/block
#pragma unroll
    for (int t = 0; t < 4; ++t) {
      size_t i = base + t * 256 + tid;         // lane-consecutive
      float4 v = ((const float4*)x)[i];
      ushort4 o;
      o.x = f32_to_bf16_bits(v.x);
      o.y = f32_to_bf16_bits(v.y);
      o.z = f32_to_bf16_bits(v.z);
      o.w = f32_to_bf16_bits(v.w);
      ((ushort4*)Xb)[i] = o;
    }
    return;
  }
  const float* src;
  unsigned short* dst;
  int NC, off;
  float scale = 1.0f;
  switch (task) {
    case 1: src = Wq; dst = Wqkv; NC = 2048; off = 0;    scale = qscale; break;
    case 2: src = Wk; dst = Wqkv; NC = 512;  off = 2048; break;
    case 3: src = Wv; dst = Wqkv; NC = 512;  off = 2560; break;
    default: src = Wo; dst = Wot; NC = 2048; off = 0;    break;
  }
  const int nbn = NC >> 6;                     // 64-col n-blocks
  if (blockIdx.x >= 32 * nbn) return;          // 32 k-blocks of 64
  const int n0 = (blockIdx.x % nbn) * 64, k0 = (blockIdx.x / nbn) * 64;

  __shared__ float tile[64][68];               // row stride 272B (16B-aligned)
  const int tx = tid & 15, ty = tid >> 4;      // 16x16 load threads
#pragma unroll
  for (int i = 0; i < 4; ++i) {
    float4 v = *(const float4*)&src[(size_t)(k0 + i * 16 + ty) * NC + n0 + tx * 4];
    *(float4*)&tile[i * 16 + ty][tx * 4] = v;
  }
  __syncthreads();
  const int n = tid >> 2, kc = (tid & 3) * 16; // 4 threads/row, 16 k each
  unsigned short* drow = dst + (size_t)(off + n0 + n) * 2048 + k0 + kc;
#pragma unroll
  for (int h = 0; h < 2; ++h) {
    u16x8 o;
#pragma unroll
    for (int j = 0; j < 8; ++j)
      o[j] = f32_to_bf16_bits(tile[kc + h * 8 + j][n] * scale);
    *(u16x8*)(drow + h * 8) = o;
  }
}

// ---------- pre-transpose V: QKV[:,2560+kv*64+d] -> Vtg[(bkv*64+d)*2048 + n] ----------
__global__ __launch_bounds__(256) void transpose_v(
    const unsigned short* __restrict__ QKV, unsigned short* __restrict__ Vtg) {
  __shared__ unsigned short t[64][72];
  int nt = blockIdx.x, bkv = blockIdx.y;
  int b = bkv >> 3, kv = bkv & 7;
  int tid = threadIdx.x;
  int row = tid >> 2, c = (tid & 3) * 16;
  const unsigned short* src =
      QKV + (size_t)(b * N_ + nt * 64 + row) * NQKV_ + 2560 + kv * 64;
  *(u16x8*)&t[row][c]     = *(const u16x8*)(src + c);
  *(u16x8*)&t[row][c + 8] = *(const u16x8*)(src + c + 8);
  __syncthreads();
  int d = tid >> 2;
  unsigned short* dst = Vtg + ((size_t)bkv * 64 + d) * N_ + nt * 64 + c;
  u16x8 o0, o1;
#pragma unroll
  for (int i = 0; i < 8; ++i) { o0[i] = t[c + i][d]; o1[i] = t[c + 8 + i][d]; }
  *(u16x8*)dst = o0;
  *(u16x8*)(dst + 8) = o1;
}

// ------------- bf16 GEMM, BM x BN tile, 8-wave (2x4), BK=64 (R7 schedule) -------------
template <int BM, int BN, bool OUT_BF16, bool BIAS>
__global__ __launch_bounds__(512, 2) void gemm256p(
    const unsigned short* __restrict__ A,
    const unsigned short* __restrict__ Bt,
    void* __restrict__ Cv,
    const float* __restrict__ bias,
    int Nn, int K, int nbx) {
  constexpr int AL = BM / 64;                  // A gloads/thread/stage
  constexpr int BL = BN / 64;                  // B gloads/thread/stage
  constexpr int STL = AL + BL;
  constexpr int RM = BM / 2;                   // rows per wave
  constexpr int CW = BN / 4;                   // cols per wave
  constexpr int MI = RM / 16;
  constexpr int NI = CW / 16;
  constexpr int NP = MI / 2;                   // MFMA clusters (A pairs)

  __shared__ unsigned short ldsA[2][BM * 64];
  __shared__ unsigned short ldsB[2][BN * 64];

  const int tid = threadIdx.x;
  const int lane = tid & 63;
  const int wave = tid >> 6;                   // 0..7
  const int wm = wave >> 2, wn = wave & 3;     // 2x4 wave grid
  const int l16 = lane & 15, quad = lane >> 4;

  // T1: XCD-aware bijective swizzle (grid = 256, multiple of 8)
  const int nwg = gridDim.x;
  const int orig = blockIdx.x;
  const int bid = (orig & 7) * (nwg >> 3) + (orig >> 3);
  const int m0 = (bid / nbx) * BM, n0 = (bid % nbx) * BN;

  const int T = K >> 6;                        // K-tiles of 64

  auto stage = [&](int c) {
    const int buf = c & 1;
#pragma unroll
    for (int i = 0; i < AL; ++i) {
      int off = i * 8192 + tid * 16;
      int row = off >> 7;
      int kch = ((off >> 4) & 7) ^ (row & 7);
      gload_lds16(A + (size_t)(m0 + row) * K + c * 64 + kch * 8,
                  (char*)&ldsA[buf][0] + off);
    }
#pragma unroll
    for (int i = 0; i < BL; ++i) {
      int off = i * 8192 + tid * 16;
      int row = off >> 7;
      int kch = ((off >> 4) & 7) ^ (row & 7);
      gload_lds16(Bt + (size_t)(n0 + row) * K + c * 64 + kch * 8,
                  (char*)&ldsB[buf][0] + off);
    }
  };

  const int sw7 = l16 & 7;
  const int cA0 = ((0 * 4 + quad) ^ sw7) * 16;
  const int cA1 = ((1 * 4 + quad) ^ sw7) * 16;
  const int rowA = (wm * RM + l16) * 128;      // byte row base, + mi*2048
  const int rowB = (wn * CW + l16) * 128;      // + ni*2048

  f32x4 acc[MI][NI] = {};

  stage(0);
  stage(1);

  for (int c = 0; c < T; ++c) {
    if (c + 1 < T) {
      if constexpr (STL == 6)      asm volatile("s_waitcnt vmcnt(6)" ::: "memory");
      else if constexpr (STL == 7) asm volatile("s_waitcnt vmcnt(7)" ::: "memory");
      else                         asm volatile("s_waitcnt vmcnt(8)" ::: "memory");
    } else {
      asm volatile("s_waitcnt vmcnt(0)" ::: "memory");
    }
    __builtin_amdgcn_s_barrier();
    asm volatile("" ::: "memory");             // pin LDS reads below barrier

    const char* Ar = (const char*)&ldsA[c & 1][0];
    const char* Br = (const char*)&ldsB[c & 1][0];

    // batch 1: all B fragments (reg-resident for whole K-tile) + A pair 0
    bf16x8 b[NI][2];
#pragma unroll
    for (int ni = 0; ni < NI; ++ni) {
      b[ni][0] = *(const bf16x8*)(Br + rowB + ni * 2048 + cA0);
      b[ni][1] = *(const bf16x8*)(Br + rowB + ni * 2048 + cA1);
    }
    bf16x8 ap[2][2][2];                        // [pair parity][mi_loc][ks]
#pragma unroll
    for (int ml = 0; ml < 2; ++ml) {
      ap[0][ml][0] = *(const bf16x8*)(Ar + rowA + ml * 2048 + cA0);
      ap[0][ml][1] = *(const bf16x8*)(Ar + rowA + ml * 2048 + cA1);
    }
    asm volatile("s_waitcnt lgkmcnt(0)" ::: "memory");
    __builtin_amdgcn_sched_barrier(0);

#pragma unroll
    for (int p = 0; p < NP; ++p) {
      if (p < NP - 1) {                        // prefetch next A pair
        const int nx = (p + 1) & 1;
#pragma unroll
        for (int ml = 0; ml < 2; ++ml) {
          int mi = (p + 1) * 2 + ml;
          ap[nx][ml][0] = *(const bf16x8*)(Ar + rowA + mi * 2048 + cA0);
          ap[nx][ml][1] = *(const bf16x8*)(Ar + rowA + mi * 2048 + cA1);
        }
      }
      __builtin_amdgcn_sched_barrier(0);
      __builtin_amdgcn_s_setprio(1);
#pragma unroll
      for (int ml = 0; ml < 2; ++ml)
#pragma unroll
        for (int ni = 0; ni < NI; ++ni)
#pragma unroll
          for (int ks = 0; ks < 2; ++ks)
            acc[p * 2 + ml][ni] = __builtin_amdgcn_mfma_f32_16x16x32_bf16(
                ap[p & 1][ml][ks], b[ni][ks], acc[p * 2 + ml][ni], 0, 0, 0);
      __builtin_amdgcn_s_setprio(0);
      if (p < NP - 1) {
        asm volatile("s_waitcnt lgkmcnt(0)" ::: "memory");
        __builtin_amdgcn_sched_barrier(0);
      }
    }

    asm volatile("" ::: "memory");
    __builtin_amdgcn_s_barrier();              // all waves' reads retired
    asm volatile("" ::: "memory");
    if (c + 2 < T) stage(c + 2);               // overwrite this buf for c+2
  }

  // epilogue
  unsigned short* Cb = (unsigned short*)Cv;
  float* Cf = (float*)Cv;
#pragma unroll
  for (int mi = 0; mi < MI; ++mi) {
    int rrow = m0 + wm * RM + mi * 16 + quad * 4;
#pragma unroll
    for (int ni = 0; ni < NI; ++ni) {
      int col = n0 + wn * CW + ni * 16 + l16;
      float bv = BIAS ? bias[col] : 0.0f;
#pragma unroll
      for (int r = 0; r < 4; ++r) {
        float v = acc[mi][ni][r] + bv;
        if (OUT_BF16)
          Cb[(size_t)(rrow + r) * Nn + col] = f32_to_bf16_bits(v);
        else
          Cf[(size_t)(rrow + r) * Nn + col] = v;
      }
    }
  }
}

// ---------------- flash attention (causal) — R10 verified version ----------------
// 8 waves x 1 strip (512 thr); wave = (head = kv*4+hp*2+(wave>>2)) x 16-row
// strip ((wave&3)*16). K/V LDS dbuf via global_load_lds; Ps [2][8][16*64].
// launch_bounds(512,4) -> 2 blocks/CU. Q pre-scaled by (1/8)*log2(e) in Wq.
__global__ __launch_bounds__(512, 4) void attn_fwd(
    const unsigned short* __restrict__ QKV,   // (4096, 3072) bf16 [Q|K|V]
    const unsigned short* __restrict__ Vtg,   // (16*64, 2048) bf16 V^T per (b,kv)
    unsigned short* __restrict__ Ctx) {       // (4096, 2048) bf16
  __shared__ unsigned short Ks[2][64 * 64];     // 16 KB
  __shared__ unsigned short Vs[2][64 * 64];     // 16 KB
  __shared__ unsigned short Ps[2][8][16 * 64];  // 32 KB [parity][wave]

  const int p = blockIdx.x;                      // 0..15
  const int kv = blockIdx.y >> 1, hp = blockIdx.y & 1;
  const int b = blockIdx.z;
  const int tid = threadIdx.x, lane = tid & 63, wave = tid >> 6;  // 0..7
  const int l16 = lane & 15, quad = lane >> 4;
  const int h = kv * 4 + hp * 2 + (wave >> 2);
  const int rstrip = (wave & 3) * 16;
  const size_t baserow = (size_t)b * N_;
  const unsigned short* Kg = QKV + 2048 + kv * 64;
  const unsigned short* Vg = Vtg + (size_t)(b * KV_ + kv) * 64 * N_;
  const unsigned short* Qbase = QKV + baserow * NQKV_ + h * 64;
  const int sw = l16 & 7;

  auto stageKV = [&](int j, int buf) {
    int c = tid;                               // 512 chunks of 16B = 8KB tile
    int row = c >> 3, off = ((c & 7) ^ (row & 7)) * 8;
    gload_lds16(Kg + (baserow + j * 64 + row) * NQKV_ + off,
                (char*)Ks[buf] + c * 16);
    gload_lds16(Vg + (size_t)row * N_ + j * 64 + off,
                (char*)Vs[buf] + c * 16);
  };

#pragma unroll 1
  for (int phase = 0; phase < 2; ++phase) {
    const int qtile = phase ? p : 31 - p;
    const int q0 = qtile * 64;

    // Q fragments direct from global (A-layout: row=l16, k=quad*8+j)
    bf16x8 qa[2];
#pragma unroll
    for (int ks = 0; ks < 2; ++ks)
      qa[ks] = *(const bf16x8*)(Qbase +
          (size_t)(q0 + rstrip + l16) * NQKV_ + ks * 32 + quad * 8);

    f32x4 oacc[4] = {};
    float lp[4] = {};

    __syncthreads();            // previous phase's K/V readers done
    stageKV(0, 0);

    for (int j = 0; j <= qtile; ++j) {
      __syncthreads();          // staged buf visible (drains vmcnt)
      const int buf = j & 1;
      if (j < qtile) stageKV(j + 1, buf ^ 1);

      // K fragments
      bf16x8 kb[2][4];
#pragma unroll
      for (int ks = 0; ks < 2; ++ks)
#pragma unroll
        for (int ni = 0; ni < 4; ++ni)
          kb[ks][ni] = *(const bf16x8*)&Ks[buf][(ni * 16 + l16) * 64 +
                                               ((ks * 4 + quad) ^ sw) * 8];

      // S = Q K^T -> mask -> exp2 -> pack to Ps[parity][wave]
      f32x4 sc[4] = {};
      __builtin_amdgcn_s_setprio(1);
#pragma unroll
      for (int ks = 0; ks < 2; ++ks)
#pragma unroll
        for (int ni = 0; ni < 4; ++ni)
          sc[ni] = __builtin_amdgcn_mfma_f32_16x16x32_bf16(
              qa[ks], kb[ks][ni], sc[ni], 0, 0, 0);
      __builtin_amdgcn_s_setprio(0);
      if (j == qtile) {   // causal mask, diagonal tile only
        const int qrow = q0 + rstrip + quad * 4;
#pragma unroll
        for (int ni = 0; ni < 4; ++ni) {
          int kcol = q0 + ni * 16 + l16;
#pragma unroll
          for (int r = 0; r < 4; ++r)
            if (kcol > qrow + r) sc[ni][r] = -1e30f;
        }
      }
      unsigned short* Pw = &Ps[buf][wave][0];
#pragma unroll
      for (int ni = 0; ni < 4; ++ni) {
        const int cl = ni * 2 + (l16 >> 3);
#pragma unroll
        for (int r = 0; r < 4; ++r) {
          float pe = __builtin_amdgcn_exp2f(sc[ni][r]);
          lp[r] += pe;
          int row = quad * 4 + r;
          Pw[row * 64 + ((cl ^ (row & 7)) * 8) + (l16 & 7)] =
              (unsigned short)(__float_as_uint(pe) >> 16);
        }
      }

      // V fragments + P read back in A-layout; PV MFMA
      bf16x8 vb[2][4];
#pragma unroll
      for (int ks = 0; ks < 2; ++ks)
#pragma unroll
        for (int di = 0; di < 4; ++di)
          vb[ks][di] = *(const bf16x8*)&Vs[buf][(di * 16 + l16) * 64 +
                                               ((ks * 4 + quad) ^ sw) * 8];
      bf16x8 pa[2];
#pragma unroll
      for (int ks = 0; ks < 2; ++ks)
        pa[ks] = *(const bf16x8*)&Ps[buf][wave][l16 * 64 +
                                               ((ks * 4 + quad) ^ sw) * 8];
      __builtin_amdgcn_s_setprio(1);
#pragma unroll
      for (int ks = 0; ks < 2; ++ks)
#pragma unroll
        for (int di = 0; di < 4; ++di)
          oacc[di] = __builtin_amdgcn_mfma_f32_16x16x32_bf16(
              pa[ks], vb[ks][di], oacc[di], 0, 0, 0);
      __builtin_amdgcn_s_setprio(0);
    }

    // normalize + write
    float inv[4];
#pragma unroll
    for (int r = 0; r < 4; ++r) {
      float v = lp[r];
#pragma unroll
      for (int off = 1; off < 16; off <<= 1) v += __shfl_xor(v, off);
      inv[r] = 1.0f / v;
    }
#pragma unroll
    for (int di = 0; di < 4; ++di)
#pragma unroll
      for (int r = 0; r < 4; ++r) {
        size_t row = baserow + q0 + rstrip + quad * 4 + r;
        Ctx[row * 2048 + h * 64 + di * 16 + l16] =
            f32_to_bf16_bits(oacc[di][r] * inv[r]);
      }
  }
}

extern "C" void kernel_launch(void* const* d_in, const int* in_sizes, int n_in,
                              void* d_out, int out_size, void* d_ws, size_t ws_size,
                              hipStream_t stream) {
  const float* x  = (const float*)d_in[0];
  const float* Wq = (const float*)d_in[1];
  const float* Wk = (const float*)d_in[2];
  const float* Wv = (const float*)d_in[3];
  const float* Wo = (const float*)d_in[4];
  const float* bo = (const float*)d_in[5];
  float* out = (float*)d_out;

  // workspace layout (bf16 = ushort): 60 MB total
  unsigned short* Xb   = (unsigned short*)d_ws;              // 4096x2048 (16 MB)
  unsigned short* Wqkv = Xb + (size_t)M_ * DIN_;             // 3072x2048 (12 MB)
  unsigned short* QKV  = Wqkv + (size_t)NQKV_ * DIN_;        // 4096x3072 (24 MB)
  unsigned short* Wot  = QKV + (size_t)M_ * NQKV_;           // 2048x2048 (8 MB)
  unsigned short* Ctx  = Xb;    // alias: Xb dead after QKV GEMM
  unsigned short* Vtg  = Wqkv;  // alias: Wqkv dead after QKV GEMM (4 MB)

  const float kQScale = 0.125f * 1.44269504088896340736f;  // (1/sqrt(DH)) * log2(e)

  prep<<<dim3(2048, 5), 256, 0, stream>>>(x, Wq, Wk, Wv, Wo, Xb, Wqkv, Wot, kQScale);

  // QKV GEMM: (4096x2048) @ (3072x2048)^T, 256x192 tiles -> 16x16 = 256 blocks
  gemm256p<256, 192, true, false><<<dim3(256), 512, 0, stream>>>(
      Xb, Wqkv, QKV, nullptr, NQKV_, DIN_, NQKV_ / 192);

  transpose_v<<<dim3(N_ / 64, B_ * KV_), 256, 0, stream>>>(QKV, Vtg);

  attn_fwd<<<dim3(16, 16, 2), 512, 0, stream>>>(QKV, Vtg, Ctx);

  // out GEMM: (4096x2048) @ (2048x2048)^T, 256x128 tiles -> 16x16 = 256 blocks
  gemm256p<256, 128, false, true><<<dim3(256), 512, 0, stream>>>(
      Ctx, Wot, out, bo, DIN_, 2048, DIN_ / 128);
}